// Round 3
// baseline (1555.143 us; speedup 1.0000x reference)
//
#include <hip/hip_runtime.h>
#include <hip/hip_bf16.h>

typedef __hip_bfloat16 bf16;

__device__ __forceinline__ float b2f(bf16 v){ return __bfloat162float(v); }
__device__ __forceinline__ bf16  f2b(float v){ return __float2bfloat16(v); }
// dtype-adaptive input load
__device__ __forceinline__ float ldx(const void* p, size_t i, int isf){
    return isf ? ((const float*)p)[i] : b2f(((const bf16*)p)[i]);
}

#define BB   16
#define CC   64
#define HH   144
#define WW   144
#define HS   48
#define SP   (HS*HS)            // 2304
#define NTOT (BB*CC*HH*WW)      // 21233664
#define NCH  36864              // B*SP, elements per channel for BN

// -------- 0. dtype sniffer: any bf16-half with exp 0xFF => input is fp32 ---
__global__ void k_sniff(const unsigned int* __restrict__ x, int* __restrict__ flag){
    __shared__ int hit;
    if(threadIdx.x==0) hit = 0;
    __syncthreads();
    int local = 0;
    for(int t=threadIdx.x; t<4096; t+=256){
        unsigned int w = x[t];
        if(((w>>7)&0xFFu)==0xFFu || ((w>>23)&0xFFu)==0xFFu) local = 1;
    }
    if(local) atomicOr(&hit, 1);
    __syncthreads();
    if(threadIdx.x==0) *flag = hit;
}

// -------- zero the stats accumulators (ws is poisoned each launch) ---------
__global__ void k_zero(float* __restrict__ p){
    int t = threadIdx.x;
    for(int i=t; i<1152; i+=256) p[i] = 0.f;
}

// -------- 1. maxpool 3x3 s1 p1 : x -> pool (bf16, stored in d_out) ---------
__global__ __launch_bounds__(256) void k_pool(const void* __restrict__ x,
                                              bf16* __restrict__ pool,
                                              const int* __restrict__ flag){
    int isf = *flag;
    int idx = blockIdx.x*256 + threadIdx.x;
    if(idx >= NTOT) return;
    int w  = idx % WW;
    int h  = (idx/WW) % HH;
    size_t bc = (size_t)(idx/(WW*HH));
    size_t base = bc*HH*WW;
    float m = -INFINITY;
    for(int dh=-1; dh<=1; ++dh){
        int hh = h+dh; if(hh<0||hh>=HH) continue;
        for(int dw=-1; dw<=1; ++dw){
            int ww2 = w+dw; if(ww2<0||ww2>=WW) continue;
            m = fmaxf(m, ldx(x, base + (size_t)hh*WW + ww2, isf));
        }
    }
    pool[idx] = f2b(m);
}

// -------- 2. on-the-fly mixer + BN1 stats (atomic) -------------------------
// block = (b,g,y): computes mixed[b, g*64+o, y, xx] for o<64, xx<48,
// reduces per-o sum/sumsq, atomicAdd into sum1/ss1[576].
__global__ __launch_bounds__(256) void k_mixstats(const bf16* __restrict__ pool,
        const void* __restrict__ wmix, float* __restrict__ sum1,
        float* __restrict__ ss1, const int* __restrict__ flag){
    __shared__ float sW[4096];
    __shared__ float sI[3072];
    __shared__ float sV[3072];
    int isf = *flag;
    int bid = blockIdx.x;
    int y = bid % HS, g = (bid/HS) % 9, b = bid/(HS*9);
    int gi = g/3, gj = g%3;
    int tid = threadIdx.x;
    for(int t=tid; t<4096; t+=256) sW[t] = ldx(wmix, (size_t)g*4096 + t, isf);
    int row = 3*y + gi;
    for(int t=tid; t<3072; t+=256){
        int i = t/48, xx = t%48;
        sI[t] = b2f(pool[ ((size_t)(b*64+i)*HH + row)*WW + 3*xx + gj ]);
    }
    __syncthreads();
    for(int t=tid; t<3072; t+=256){
        int o = t/48, xx = t%48;
        float acc = 0.f;
        const float* wr = &sW[o*64];
        const float* ir = &sI[xx];
        #pragma unroll 8
        for(int i=0;i<64;++i) acc += wr[i]*ir[i*48];
        sV[t] = acc;
    }
    __syncthreads();
    if(tid < 64){
        float s = 0.f, q = 0.f;
        const float* v = &sV[tid*48];
        for(int k=0;k<48;++k){ float a=v[k]; s+=a; q+=a*a; }
        atomicAdd(&sum1[g*64+tid], s);
        atomicAdd(&ss1 [g*64+tid], q);
    }
}

// -------- 3. finalize BN1 stats --------------------------------------------
__global__ void k_finstats(const float* __restrict__ sum1, const float* __restrict__ ss1,
                           float* __restrict__ mean1, float* __restrict__ istd1){
    int t = blockIdx.x*256 + threadIdx.x;
    if(t < 576){
        float m = sum1[t]/(float)NCH;
        float v = ss1[t]/(float)NCH - m*m;
        mean1[t] = m;
        istd1[t] = rsqrtf(v + 1e-5f);
    }
}

// -------- 4. tem = BN1(mixed group 0)  (bf16, in ws) -----------------------
__global__ __launch_bounds__(256) void k_tem(const bf16* __restrict__ pool,
        const void* __restrict__ wmix, const void* __restrict__ gm,
        const void* __restrict__ bm, const float* __restrict__ mean1,
        const float* __restrict__ istd1, bf16* __restrict__ tem,
        const int* __restrict__ flag){
    __shared__ float sW[4096];
    __shared__ float sI[3072];
    int isf = *flag;
    int bid = blockIdx.x;
    int y = bid % HS, b = bid/HS;
    int tid = threadIdx.x;
    for(int t=tid; t<4096; t+=256) sW[t] = ldx(wmix, t, isf);   // g=0
    for(int t=tid; t<3072; t+=256){
        int i = t/48, xx = t%48;
        sI[t] = b2f(pool[ ((size_t)(b*64+i)*HH + 3*y)*WW + 3*xx ]);
    }
    __syncthreads();
    for(int t=tid; t<3072; t+=256){
        int o = t/48, xx = t%48;
        float acc = 0.f;
        const float* wr = &sW[o*64];
        const float* ir = &sI[xx];
        #pragma unroll 8
        for(int i=0;i<64;++i) acc += wr[i]*ir[i*48];
        float v = (acc - mean1[o])*istd1[o]*ldx(gm,o,isf) + ldx(bm,o,isf);
        tem[ ((size_t)(b*64+o)*HS + y)*HS + xx ] = f2b(v);
    }
}

// -------- 5. fused 4-way depthwise conv (direct formulas incl. shears) -----
// att aliases tem: block (b,c) reads whole plane into LDS before any write.
__global__ __launch_bounds__(256) void k_conv(const bf16* __restrict__ tem,
    const void* __restrict__ wh1, const void* __restrict__ wv1,
    const void* __restrict__ wh2, const void* __restrict__ wv2,
    bf16* __restrict__ att, const int* __restrict__ flag){
    __shared__ float tile[60*60];
    __shared__ float wt[4*33];
    int isf = *flag;
    int bid = blockIdx.x;
    int b = bid/64, c = bid%64;
    int tid = threadIdx.x;
    for(int t=tid; t<3600; t+=256) tile[t] = 0.f;
    if(tid < 132){
        int which = tid/33, k = tid%33;
        const void* wp = which==0?wh1:which==1?wv1:which==2?wh2:wv2;
        wt[tid] = ldx(wp, c*33 + k, isf);
    }
    __syncthreads();
    const bf16* src = tem + (size_t)(b*64 + c)*SP;
    for(int t=tid; t<SP; t+=256){
        int h = t/48, w = t%48;
        tile[(h+6)*60 + (w+6)] = b2f(src[t]);
    }
    __syncthreads();
    bf16* out = att + (size_t)(b*64 + c)*SP;
    for(int t=tid; t<SP; t+=256){
        int h = t/48 + 6, w = t%48 + 6;
        float acc = 0.f;
        #pragma unroll
        for(int u=-5; u<=5; ++u)
            #pragma unroll
            for(int v=-1; v<=1; ++v)
                acc += wt[0*33 + (u+5)*3 + (v+1)] * tile[(h+u)*60 + (w+v)];
        #pragma unroll
        for(int u=-1; u<=1; ++u)
            #pragma unroll
            for(int v=-5; v<=5; ++v)
                acc += wt[1*33 + (u+1)*11 + (v+5)] * tile[(h+u)*60 + (w+v)];
        #pragma unroll
        for(int u=-5; u<=5; ++u)
            #pragma unroll
            for(int v=-1; v<=1; ++v)
                acc += wt[2*33 + (u+5)*3 + (v+1)] * tile[(h+u)*60 + (w+v-u)];
        #pragma unroll
        for(int u=-5; u<=5; ++u)
            #pragma unroll
            for(int v=-1; v<=1; ++v)
                acc += wt[3*33 + (v+1)*11 + (u+5)] * tile[(h+v-u)*60 + (w+u)];
        out[t] = f2b(acc);
    }
}

// -------- 6. BN2 stats over att (64 ch) ------------------------------------
__global__ __launch_bounds__(256) void k_stats2(const bf16* __restrict__ in,
                                                float* __restrict__ mean,
                                                float* __restrict__ istd){
    __shared__ float s1[256], s2[256];
    int ch = blockIdx.x, tid = threadIdx.x;
    float sum = 0.f, ss = 0.f;
    for(int t=tid; t<NCH; t+=256){
        int b = t/SP, sp = t%SP;
        float v = b2f(in[ ((size_t)(b*64) + ch)*SP + sp ]);
        sum += v; ss += v*v;
    }
    s1[tid]=sum; s2[tid]=ss; __syncthreads();
    for(int o=128;o>0;o>>=1){
        if(tid<o){ s1[tid]+=s1[tid+o]; s2[tid]+=s2[tid+o]; }
        __syncthreads();
    }
    if(tid==0){
        float m = s1[0]/(float)NCH;
        float var = s2[0]/(float)NCH - m*m;
        mean[ch] = m;
        istd[ch] = rsqrtf(var + 1e-5f);
    }
}

// -------- 7. final: recompute pool3+mixed(g>=1) in LDS, BN, shuffle, gate --
// block (b,y): reads x (input) / wmix / ws only; writes out rows 3y..3y+2.
// No reads of d_out => pool-in-d_out is safe for both dtype cases.
__global__ __launch_bounds__(256) void k_final(const void* __restrict__ x,
    const void* __restrict__ wmix, const bf16* __restrict__ att,
    const void* __restrict__ gm, const void* __restrict__ bm,
    const void* __restrict__ gn, const void* __restrict__ bnb,
    const float* __restrict__ mean1, const float* __restrict__ istd1,
    const float* __restrict__ mean2, const float* __restrict__ istd2,
    void* __restrict__ out, const int* __restrict__ flag){
    __shared__ bf16 sW[8*4096];     // groups 1..8, 65536 B
    __shared__ bf16 p3[64*3*144];   // pool rows 3y..3y+2, 55296 B
    __shared__ bf16 sA[64*48];      // att row y, 6144 B
    __shared__ float sc1[512], sh1[512]; // bn1 scale/shift for f>=64, 4096 B
    int isf = *flag;
    int bid = blockIdx.x;
    int y = bid % HS, b = bid/HS;
    int tid = threadIdx.x;
    for(int t=tid; t<32768; t+=256) sW[t] = f2b(ldx(wmix, 4096 + (size_t)t, isf));
    for(int t=tid; t<3072; t+=256){
        int f = t/48, xx = t%48;
        sA[t] = att[ ((size_t)(b*64+f)*HS + y)*HS + xx ];
    }
    for(int t=tid; t<512; t+=256){
        int f = t + 64;
        float g = ldx(gm,f,isf), be = ldx(bm,f,isf);
        float sc = istd1[f]*g;
        sc1[t] = sc;
        sh1[t] = be - mean1[f]*sc;
    }
    for(int t=tid; t<27648; t+=256){
        int col = t % 144;
        int q   = (t/144) % 3;
        int i   = t/432;
        int R   = 3*y + q;
        size_t base = (size_t)(b*64 + i)*HH;
        float m = -INFINITY;
        for(int dr=-1; dr<=1; ++dr){
            int rr = R+dr; if(rr<0||rr>=HH) continue;
            for(int dc=-1; dc<=1; ++dc){
                int cc = col+dc; if(cc<0||cc>=WW) continue;
                m = fmaxf(m, ldx(x, (base+rr)*WW + cc, isf));
            }
        }
        p3[(i*3+q)*144 + col] = f2b(m);
    }
    __syncthreads();
    for(int t=tid; t<27648; t+=256){
        int xx = t % 48;
        int f  = t / 48;
        float v;
        if(f < 64){
            v = (b2f(sA[f*48+xx]) - mean2[f])*istd2[f]*ldx(gn,f,isf) + ldx(bnb,f,isf);
        } else {
            int g = f>>6, o = f&63;
            int gi = g/3, gj = g%3;
            const bf16* wr = &sW[((g-1)*64 + o)*64];
            const bf16* pr = &p3[gi*144 + 3*xx + gj];
            float acc = 0.f;
            #pragma unroll 8
            for(int i=0;i<64;++i) acc += b2f(wr[i])*b2f(pr[i*432]);
            v = acc*sc1[f-64] + sh1[f-64];
        }
        int c = f/9, rs = f%9, r = rs/3, s = rs%3;
        size_t oi = ((size_t)(b*64+c)*HH + 3*y + r)*WW + 3*xx + s;
        float sg = 1.f/(1.f + __expf(-v));
        float ov = ldx(x, oi, isf) * sg;
        if(isf) ((float*)out)[oi] = ov;
        else    ((bf16*)out)[oi] = f2b(ov);
    }
}

extern "C" void kernel_launch(void* const* d_in, const int* in_sizes, int n_in,
                              void* d_out, int out_size, void* d_ws, size_t ws_size,
                              hipStream_t stream) {
    (void)in_sizes; (void)n_in; (void)out_size; (void)ws_size;
    const void* x    = d_in[0];
    const void* wmix = d_in[1];
    const void* gm   = d_in[2];
    const void* bm   = d_in[3];
    const void* wh1  = d_in[4];
    const void* wv1  = d_in[5];
    const void* wh2  = d_in[6];
    const void* wv2  = d_in[7];
    const void* gn   = d_in[8];
    const void* bnb  = d_in[9];

    // workspace: 4.73 MB total
    char* ws = (char*)d_ws;
    bf16*  tem   = (bf16*) (ws + 0);          // 4718592 B (att aliases tem)
    float* sum1  = (float*)(ws + 4718592);    // 2304 B (ss1 contiguous after)
    float* ss1   = (float*)(ws + 4720896);
    float* mean1 = (float*)(ws + 4723200);
    float* istd1 = (float*)(ws + 4725504);
    float* mean2 = (float*)(ws + 4727808);    // 256 B
    float* istd2 = (float*)(ws + 4728064);
    int*   flag  = (int*)  (ws + 4728320);
    bf16*  pool  = (bf16*) d_out;             // scratch; k_final overwrites d_out
    bf16*  att   = tem;

    k_sniff   <<<1, 256, 0, stream>>>((const unsigned int*)x, flag);
    k_pool    <<<(NTOT+255)/256, 256, 0, stream>>>(x, pool, flag);
    k_zero    <<<1, 256, 0, stream>>>(sum1);
    k_mixstats<<<BB*9*HS, 256, 0, stream>>>(pool, wmix, sum1, ss1, flag);
    k_finstats<<<3, 256, 0, stream>>>(sum1, ss1, mean1, istd1);
    k_tem     <<<BB*HS, 256, 0, stream>>>(pool, wmix, gm, bm, mean1, istd1, tem, flag);
    k_conv    <<<BB*64, 256, 0, stream>>>(tem, wh1, wv1, wh2, wv2, att, flag);
    k_stats2  <<<64, 256, 0, stream>>>(att, mean2, istd2);
    k_final   <<<BB*HS, 256, 0, stream>>>(x, wmix, att, gm, bm, gn, bnb,
                                          mean1, istd1, mean2, istd2, d_out, flag);
}

// Round 4
// 454.054 us; speedup vs baseline: 3.4250x; 3.4250x over previous
//
#include <hip/hip_runtime.h>
#include <hip/hip_bf16.h>

typedef __hip_bfloat16 bf16;

__device__ __forceinline__ float b2f(bf16 v){ return __bfloat162float(v); }
__device__ __forceinline__ bf16  f2b(float v){ return __float2bfloat16(v); }
__device__ __forceinline__ float ldx(const void* p, size_t i, int isf){
    return isf ? ((const float*)p)[i] : b2f(((const bf16*)p)[i]);
}
__device__ __forceinline__ unsigned short bfbits(float v){
    bf16 h = f2b(v);
    return *(unsigned short*)&h;
}

#define BB   16
#define CC   64
#define HH   144
#define WW   144
#define HS   48
#define SP   (HS*HS)            // 2304
#define NTOT (BB*CC*HH*WW)      // 21233664
#define NCH  36864              // B*SP

// ===================== shared by both paths ================================

// -------- 0. dtype sniffer -------------------------------------------------
__global__ void k_sniff(const unsigned int* __restrict__ x, int* __restrict__ flag){
    __shared__ int hit;
    if(threadIdx.x==0) hit = 0;
    __syncthreads();
    int local = 0;
    for(int t=threadIdx.x; t<4096; t+=256){
        unsigned int w = x[t];
        if(((w>>7)&0xFFu)==0xFFu || ((w>>23)&0xFFu)==0xFFu) local = 1;
    }
    if(local) atomicOr(&hit, 1);
    __syncthreads();
    if(threadIdx.x==0) *flag = hit;
}

__global__ void k_zero(float* __restrict__ p){
    int t = threadIdx.x;
    for(int i=t; i<1152; i+=256) p[i] = 0.f;
}

// -------- 1. maxpool, separable, 16-row strips -----------------------------
__global__ __launch_bounds__(256) void k_pool2(const void* __restrict__ x,
                                               bf16* __restrict__ pool,
                                               const int* __restrict__ flag){
    __shared__ float l [18*148];
    __shared__ float hm[18*148];
    int isf = *flag;
    int bid = blockIdx.x;
    int strip = bid % 9;
    size_t bc = (size_t)(bid / 9);
    int r0 = strip*16;
    size_t base = bc*HH*WW;
    int tid = threadIdx.x;
    for(int t=tid; t<18*144; t+=256){
        int rr = t/144 - 1 + r0;
        int cc = t%144;
        float v = (rr>=0 && rr<HH) ? ldx(x, base + (size_t)rr*WW + cc, isf) : -INFINITY;
        l[(t/144)*148 + cc] = v;
    }
    __syncthreads();
    for(int t=tid; t<18*144; t+=256){
        int row = t/144, cc = t%144;
        float a = l[row*148+cc];
        float b = (cc>0)   ? l[row*148+cc-1] : -INFINITY;
        float c = (cc<143) ? l[row*148+cc+1] : -INFINITY;
        hm[row*148+cc] = fmaxf(a, fmaxf(b,c));
    }
    __syncthreads();
    for(int t=tid; t<16*144; t+=256){
        int row = t/144, cc = t%144;
        float m = fmaxf(hm[row*148+cc],
                  fmaxf(hm[(row+1)*148+cc], hm[(row+2)*148+cc]));
        pool[base + (size_t)(r0+row)*WW + cc] = f2b(m);
    }
}

// -------- finalize BN1 stats ----------------------------------------------
__global__ void k_finstats(const float* __restrict__ sum1, const float* __restrict__ ss1,
                           float* __restrict__ mean1, float* __restrict__ istd1){
    int t = blockIdx.x*256 + threadIdx.x;
    if(t < 576){
        float m = sum1[t]/(float)NCH;
        float v = ss1[t]/(float)NCH - m*m;
        mean1[t] = m;
        istd1[t] = rsqrtf(v + 1e-5f);
    }
}

// -------- BN2 stats over att ----------------------------------------------
__global__ __launch_bounds__(256) void k_stats2(const bf16* __restrict__ in,
                                                float* __restrict__ mean,
                                                float* __restrict__ istd){
    __shared__ float s1[256], s2[256];
    int ch = blockIdx.x, tid = threadIdx.x;
    float sum = 0.f, ss = 0.f;
    for(int t=tid; t<NCH; t+=256){
        int b = t/SP, sp = t%SP;
        float v = b2f(in[ ((size_t)(b*64) + ch)*SP + sp ]);
        sum += v; ss += v*v;
    }
    s1[tid]=sum; s2[tid]=ss; __syncthreads();
    for(int o=128;o>0;o>>=1){
        if(tid<o){ s1[tid]+=s1[tid+o]; s2[tid]+=s2[tid+o]; }
        __syncthreads();
    }
    if(tid==0){
        float m = s1[0]/(float)NCH;
        float var = s2[0]/(float)NCH - m*m;
        mean[ch] = m;
        istd[ch] = rsqrtf(var + 1e-5f);
    }
}

// ===================== FAST PATH (mixed materialized) ======================

// -------- mixer + mixed store + BN1 stats ----------------------------------
// grid (b,g,yb): 16*9*24, 192 threads. Each thread: 8 o x 4 xx x 2 y tile.
__global__ __launch_bounds__(192) void k_mix2(const bf16* __restrict__ pool,
        const void* __restrict__ wmix, bf16* __restrict__ mixed,
        float* __restrict__ sum1, float* __restrict__ ss1,
        const int* __restrict__ flag){
    __shared__ float sWt[4096];      // [i*64+o] transposed
    __shared__ float sI[2][3072];    // [y][i*48+xx]
    __shared__ float sS[64], sQ[64];
    int isf = *flag;
    int bid = blockIdx.x;
    int yb = bid % 24, g = (bid/24)%9, b = bid/(24*9);
    int gi = g/3, gj = g%3;
    int tid = threadIdx.x;
    for(int t=tid; t<4096; t+=192){
        int i = t>>6, o = t&63;
        sWt[t] = ldx(wmix, (size_t)g*4096 + o*64 + i, isf);
    }
    if(tid<64){ sS[tid]=0.f; sQ[tid]=0.f; }
    for(int t=tid; t<2*3072; t+=192){
        int y = t/3072, rem = t%3072;
        int i = rem/48, xx = rem%48;
        int row = 3*(yb*2+y) + gi;
        sI[y][rem] = b2f(pool[ ((size_t)(b*64+i)*HH + row)*WW + 3*xx + gj ]);
    }
    __syncthreads();
    int xxb = tid % 12, ob = (tid/12)%8, y = tid/96;
    int xx0 = xxb*4, o0 = ob*8;
    float acc[8][4];
    #pragma unroll
    for(int j=0;j<8;++j){
        #pragma unroll
        for(int k=0;k<4;++k) acc[j][k]=0.f;
    }
    const float* ir = &sI[y][xx0];
    #pragma unroll 4
    for(int i=0;i<64;++i){
        float4 a  = *(const float4*)&ir[i*48];
        float4 w0 = *(const float4*)&sWt[i*64+o0];
        float4 w1 = *(const float4*)&sWt[i*64+o0+4];
        float wv[8] = {w0.x,w0.y,w0.z,w0.w,w1.x,w1.y,w1.z,w1.w};
        float av[4] = {a.x,a.y,a.z,a.w};
        #pragma unroll
        for(int j=0;j<8;++j){
            #pragma unroll
            for(int k=0;k<4;++k) acc[j][k] += wv[j]*av[k];
        }
    }
    int yy = yb*2 + y;
    #pragma unroll
    for(int j=0;j<8;++j){
        int o = o0+j;
        union { unsigned short u[4]; uint2 v; } pk;
        float s=0.f, q=0.f;
        #pragma unroll
        for(int k=0;k<4;++k){
            float a = acc[j][k];
            s += a; q += a*a;
            pk.u[k] = bfbits(a);
        }
        *(uint2*)&mixed[ ((size_t)(b*576 + g*64 + o)*HS + yy)*HS + xx0 ] = pk.v;
        atomicAdd(&sS[o], s);
        atomicAdd(&sQ[o], q);
    }
    __syncthreads();
    if(tid<64){
        atomicAdd(&sum1[g*64+tid], sS[tid]);
        atomicAdd(&ss1 [g*64+tid], sQ[tid]);
    }
}

// -------- fused 4-way depthwise conv, BN1 inline ---------------------------
__global__ __launch_bounds__(256) void k_conv2(const bf16* __restrict__ mixed,
    const float* __restrict__ mean1, const float* __restrict__ istd1,
    const void* __restrict__ gm, const void* __restrict__ bm,
    const void* __restrict__ wh1, const void* __restrict__ wv1,
    const void* __restrict__ wh2, const void* __restrict__ wv2,
    bf16* __restrict__ att, const int* __restrict__ flag){
    __shared__ float tile[60*60];
    __shared__ float wt[4*33];
    int isf = *flag;
    int bid = blockIdx.x;
    int b = bid/64, c = bid%64;
    int tid = threadIdx.x;
    for(int t=tid; t<3600; t+=256) tile[t] = 0.f;
    if(tid < 132){
        int which = tid/33, k = tid%33;
        const void* wp = which==0?wh1:which==1?wv1:which==2?wh2:wv2;
        wt[tid] = ldx(wp, c*33 + k, isf);
    }
    __syncthreads();
    float m  = mean1[c];
    float is = istd1[c]*ldx(gm,c,isf);
    float be = ldx(bm,c,isf);
    const bf16* src = mixed + (size_t)(b*576 + c)*SP;
    for(int t=tid; t<SP; t+=256){
        int h = t/48, w = t%48;
        tile[(h+6)*60 + (w+6)] = (b2f(src[t]) - m)*is + be;
    }
    __syncthreads();
    bf16* out = att + (size_t)(b*64 + c)*SP;
    for(int t=tid; t<SP; t+=256){
        int h = t/48 + 6, w = t%48 + 6;
        float acc = 0.f;
        #pragma unroll
        for(int u=-5; u<=5; ++u)
            #pragma unroll
            for(int v=-1; v<=1; ++v)
                acc += wt[0*33 + (u+5)*3 + (v+1)] * tile[(h+u)*60 + (w+v)];
        #pragma unroll
        for(int u=-1; u<=1; ++u)
            #pragma unroll
            for(int v=-5; v<=5; ++v)
                acc += wt[1*33 + (u+1)*11 + (v+5)] * tile[(h+u)*60 + (w+v)];
        #pragma unroll
        for(int u=-5; u<=5; ++u)
            #pragma unroll
            for(int v=-1; v<=1; ++v)
                acc += wt[2*33 + (u+5)*3 + (v+1)] * tile[(h+u)*60 + (w+v-u)];
        #pragma unroll
        for(int u=-5; u<=5; ++u)
            #pragma unroll
            for(int v=-1; v<=1; ++v)
                acc += wt[3*33 + (v+1)*11 + (u+5)] * tile[(h+v-u)*60 + (w+u)];
        out[t] = f2b(acc);
    }
}

// -------- final: read mixed/att planes, BN, shuffle, gate ------------------
// block (b,c). LDS: 9 raw planes (bf16) + 9 scale/shift.
__global__ __launch_bounds__(256) void k_final2(const void* __restrict__ x,
    const bf16* __restrict__ mixed, const bf16* __restrict__ att,
    const void* __restrict__ gm, const void* __restrict__ bm,
    const void* __restrict__ gn, const void* __restrict__ bnb,
    const float* __restrict__ mean1, const float* __restrict__ istd1,
    const float* __restrict__ mean2, const float* __restrict__ istd2,
    void* __restrict__ out, const int* __restrict__ flag){
    __shared__ bf16  sT[9*2304];
    __shared__ float scs[9], shs[9];
    int isf = *flag;
    int bid = blockIdx.x;
    int b = bid/64, c = bid%64;
    int tid = threadIdx.x;
    if(tid < 9){
        int f = 9*c + tid;
        float sc, sh;
        if(f < 64){
            sc = istd2[f]*ldx(gn,f,isf);
            sh = ldx(bnb,f,isf) - mean2[f]*sc;
        } else {
            sc = istd1[f]*ldx(gm,f,isf);
            sh = ldx(bm,f,isf) - mean1[f]*sc;
        }
        scs[tid]=sc; shs[tid]=sh;
    }
    for(int t=tid; t<9*288; t+=256){
        int j = t/288, q = t%288;
        int f = 9*c + j;
        const bf16* src = (f<64) ? att   + (size_t)(b*64 +f)*SP
                                 : mixed + (size_t)(b*576+f)*SP;
        ((uint4*)&sT[j*2304])[q] = ((const uint4*)src)[q];
    }
    __syncthreads();
    size_t pbase = (size_t)(b*64+c)*HH*WW;
    for(int t=tid; t<2592; t+=256){
        int Y  = t/18;
        int Xb = (t%18)*8;
        int yy = Y/3, r = Y%3;
        float vo[8];
        #pragma unroll
        for(int k=0;k<8;++k){
            int X = Xb+k;
            int xx = X/3, s = X%3;
            int j = 3*r + s;
            float raw = b2f(sT[j*2304 + yy*48 + xx]);
            float v = raw*scs[j] + shs[j];
            vo[k] = 1.f/(1.f + __expf(-v));
        }
        size_t off = pbase + (size_t)Y*WW + Xb;
        if(isf){
            const float4* xp = (const float4*)((const float*)x + off);
            float4 x0 = xp[0], x1 = xp[1];
            float4 o0, o1;
            o0.x = x0.x*vo[0]; o0.y = x0.y*vo[1]; o0.z = x0.z*vo[2]; o0.w = x0.w*vo[3];
            o1.x = x1.x*vo[4]; o1.y = x1.y*vo[5]; o1.z = x1.z*vo[6]; o1.w = x1.w*vo[7];
            float4* op = (float4*)((float*)out + off);
            op[0] = o0; op[1] = o1;
        } else {
            uint4 xr = *(const uint4*)((const bf16*)x + off);
            const unsigned short* xu = (const unsigned short*)&xr;
            union { unsigned short u[8]; uint4 v; } pk;
            #pragma unroll
            for(int k=0;k<8;++k){
                unsigned int wbits = ((unsigned int)xu[k])<<16;
                float xv = *(float*)&wbits;
                pk.u[k] = bfbits(xv*vo[k]);
            }
            *(uint4*)((bf16*)out + off) = pk.v;
        }
    }
}

// ===================== FALLBACK PATH (round-3, verified) ===================

__global__ __launch_bounds__(256) void k_mixstats(const bf16* __restrict__ pool,
        const void* __restrict__ wmix, float* __restrict__ sum1,
        float* __restrict__ ss1, const int* __restrict__ flag){
    __shared__ float sW[4096];
    __shared__ float sI[3072];
    __shared__ float sV[3072];
    int isf = *flag;
    int bid = blockIdx.x;
    int y = bid % HS, g = (bid/HS) % 9, b = bid/(HS*9);
    int gi = g/3, gj = g%3;
    int tid = threadIdx.x;
    for(int t=tid; t<4096; t+=256) sW[t] = ldx(wmix, (size_t)g*4096 + t, isf);
    int row = 3*y + gi;
    for(int t=tid; t<3072; t+=256){
        int i = t/48, xx = t%48;
        sI[t] = b2f(pool[ ((size_t)(b*64+i)*HH + row)*WW + 3*xx + gj ]);
    }
    __syncthreads();
    for(int t=tid; t<3072; t+=256){
        int o = t/48, xx = t%48;
        float acc = 0.f;
        const float* wr = &sW[o*64];
        const float* ir = &sI[xx];
        #pragma unroll 8
        for(int i=0;i<64;++i) acc += wr[i]*ir[i*48];
        sV[t] = acc;
    }
    __syncthreads();
    if(tid < 64){
        float s = 0.f, q = 0.f;
        const float* v = &sV[tid*48];
        for(int k=0;k<48;++k){ float a=v[k]; s+=a; q+=a*a; }
        atomicAdd(&sum1[g*64+tid], s);
        atomicAdd(&ss1 [g*64+tid], q);
    }
}

__global__ __launch_bounds__(256) void k_tem(const bf16* __restrict__ pool,
        const void* __restrict__ wmix, const void* __restrict__ gm,
        const void* __restrict__ bm, const float* __restrict__ mean1,
        const float* __restrict__ istd1, bf16* __restrict__ tem,
        const int* __restrict__ flag){
    __shared__ float sW[4096];
    __shared__ float sI[3072];
    int isf = *flag;
    int bid = blockIdx.x;
    int y = bid % HS, b = bid/HS;
    int tid = threadIdx.x;
    for(int t=tid; t<4096; t+=256) sW[t] = ldx(wmix, t, isf);
    for(int t=tid; t<3072; t+=256){
        int i = t/48, xx = t%48;
        sI[t] = b2f(pool[ ((size_t)(b*64+i)*HH + 3*y)*WW + 3*xx ]);
    }
    __syncthreads();
    for(int t=tid; t<3072; t+=256){
        int o = t/48, xx = t%48;
        float acc = 0.f;
        const float* wr = &sW[o*64];
        const float* ir = &sI[xx];
        #pragma unroll 8
        for(int i=0;i<64;++i) acc += wr[i]*ir[i*48];
        float v = (acc - mean1[o])*istd1[o]*ldx(gm,o,isf) + ldx(bm,o,isf);
        tem[ ((size_t)(b*64+o)*HS + y)*HS + xx ] = f2b(v);
    }
}

__global__ __launch_bounds__(256) void k_conv_nb(const bf16* __restrict__ tem,
    const void* __restrict__ wh1, const void* __restrict__ wv1,
    const void* __restrict__ wh2, const void* __restrict__ wv2,
    bf16* __restrict__ att, const int* __restrict__ flag){
    __shared__ float tile[60*60];
    __shared__ float wt[4*33];
    int isf = *flag;
    int bid = blockIdx.x;
    int b = bid/64, c = bid%64;
    int tid = threadIdx.x;
    for(int t=tid; t<3600; t+=256) tile[t] = 0.f;
    if(tid < 132){
        int which = tid/33, k = tid%33;
        const void* wp = which==0?wh1:which==1?wv1:which==2?wh2:wv2;
        wt[tid] = ldx(wp, c*33 + k, isf);
    }
    __syncthreads();
    const bf16* src = tem + (size_t)(b*64 + c)*SP;
    for(int t=tid; t<SP; t+=256){
        int h = t/48, w = t%48;
        tile[(h+6)*60 + (w+6)] = b2f(src[t]);
    }
    __syncthreads();
    bf16* out = att + (size_t)(b*64 + c)*SP;
    for(int t=tid; t<SP; t+=256){
        int h = t/48 + 6, w = t%48 + 6;
        float acc = 0.f;
        #pragma unroll
        for(int u=-5; u<=5; ++u)
            #pragma unroll
            for(int v=-1; v<=1; ++v)
                acc += wt[0*33 + (u+5)*3 + (v+1)] * tile[(h+u)*60 + (w+v)];
        #pragma unroll
        for(int u=-1; u<=1; ++u)
            #pragma unroll
            for(int v=-5; v<=5; ++v)
                acc += wt[1*33 + (u+1)*11 + (v+5)] * tile[(h+u)*60 + (w+v)];
        #pragma unroll
        for(int u=-5; u<=5; ++u)
            #pragma unroll
            for(int v=-1; v<=1; ++v)
                acc += wt[2*33 + (u+5)*3 + (v+1)] * tile[(h+u)*60 + (w+v-u)];
        #pragma unroll
        for(int u=-5; u<=5; ++u)
            #pragma unroll
            for(int v=-1; v<=1; ++v)
                acc += wt[3*33 + (v+1)*11 + (u+5)] * tile[(h+v-u)*60 + (w+u)];
        out[t] = f2b(acc);
    }
}

__global__ __launch_bounds__(256) void k_final_fb(const void* __restrict__ x,
    const void* __restrict__ wmix, const bf16* __restrict__ att,
    const void* __restrict__ gm, const void* __restrict__ bm,
    const void* __restrict__ gn, const void* __restrict__ bnb,
    const float* __restrict__ mean1, const float* __restrict__ istd1,
    const float* __restrict__ mean2, const float* __restrict__ istd2,
    void* __restrict__ out, const int* __restrict__ flag){
    __shared__ bf16 sW[8*4096];
    __shared__ bf16 p3[64*3*144];
    __shared__ bf16 sA[64*48];
    __shared__ float sc1[512], sh1[512];
    int isf = *flag;
    int bid = blockIdx.x;
    int y = bid % HS, b = bid/HS;
    int tid = threadIdx.x;
    for(int t=tid; t<32768; t+=256) sW[t] = f2b(ldx(wmix, 4096 + (size_t)t, isf));
    for(int t=tid; t<3072; t+=256){
        int f = t/48, xx = t%48;
        sA[t] = att[ ((size_t)(b*64+f)*HS + y)*HS + xx ];
    }
    for(int t=tid; t<512; t+=256){
        int f = t + 64;
        float g = ldx(gm,f,isf), be = ldx(bm,f,isf);
        float sc = istd1[f]*g;
        sc1[t] = sc;
        sh1[t] = be - mean1[f]*sc;
    }
    for(int t=tid; t<27648; t+=256){
        int col = t % 144;
        int q   = (t/144) % 3;
        int i   = t/432;
        int R   = 3*y + q;
        size_t base = (size_t)(b*64 + i)*HH;
        float m = -INFINITY;
        for(int dr=-1; dr<=1; ++dr){
            int rr = R+dr; if(rr<0||rr>=HH) continue;
            for(int dc=-1; dc<=1; ++dc){
                int cc = col+dc; if(cc<0||cc>=WW) continue;
                m = fmaxf(m, ldx(x, (base+rr)*WW + cc, isf));
            }
        }
        p3[(i*3+q)*144 + col] = f2b(m);
    }
    __syncthreads();
    for(int t=tid; t<27648; t+=256){
        int xx = t % 48;
        int f  = t / 48;
        float v;
        if(f < 64){
            v = (b2f(sA[f*48+xx]) - mean2[f])*istd2[f]*ldx(gn,f,isf) + ldx(bnb,f,isf);
        } else {
            int g = f>>6, o = f&63;
            int gi = g/3, gj = g%3;
            const bf16* wr = &sW[((g-1)*64 + o)*64];
            const bf16* pr = &p3[gi*144 + 3*xx + gj];
            float acc = 0.f;
            #pragma unroll 8
            for(int i=0;i<64;++i) acc += b2f(wr[i])*b2f(pr[i*432]);
            v = acc*sc1[f-64] + sh1[f-64];
        }
        int c = f/9, rs = f%9, r = rs/3, s = rs%3;
        size_t oi = ((size_t)(b*64+c)*HH + 3*y + r)*WW + 3*xx + s;
        float sg = 1.f/(1.f + __expf(-v));
        float ov = ldx(x, oi, isf) * sg;
        if(isf) ((float*)out)[oi] = ov;
        else    ((bf16*)out)[oi] = f2b(ov);
    }
}

// ===========================================================================

extern "C" void kernel_launch(void* const* d_in, const int* in_sizes, int n_in,
                              void* d_out, int out_size, void* d_ws, size_t ws_size,
                              hipStream_t stream) {
    (void)in_sizes; (void)n_in; (void)out_size;
    const void* x    = d_in[0];
    const void* wmix = d_in[1];
    const void* gm   = d_in[2];
    const void* bm   = d_in[3];
    const void* wh1  = d_in[4];
    const void* wv1  = d_in[5];
    const void* wh2  = d_in[6];
    const void* wv2  = d_in[7];
    const void* gn   = d_in[8];
    const void* bnb  = d_in[9];

    bf16* pool = (bf16*)d_out;   // scratch in d_out; final overwrites
    char* ws = (char*)d_ws;

    bool fast = ws_size >= 47195652ull;
    if(fast){
        bf16*  mixed = (bf16*) (ws + 0);          // 42467328
        bf16*  att   = (bf16*) (ws + 42467328);   //  4718592
        float* sum1  = (float*)(ws + 47185920);
        float* ss1   = (float*)(ws + 47188224);
        float* mean1 = (float*)(ws + 47190528);
        float* istd1 = (float*)(ws + 47192832);
        float* mean2 = (float*)(ws + 47195136);
        float* istd2 = (float*)(ws + 47195392);
        int*   flag  = (int*)  (ws + 47195648);

        k_sniff   <<<1, 256, 0, stream>>>((const unsigned int*)x, flag);
        k_pool2   <<<BB*CC*9, 256, 0, stream>>>(x, pool, flag);
        k_zero    <<<1, 256, 0, stream>>>(sum1);
        k_mix2    <<<BB*9*24, 192, 0, stream>>>(pool, wmix, mixed, sum1, ss1, flag);
        k_finstats<<<3, 256, 0, stream>>>(sum1, ss1, mean1, istd1);
        k_conv2   <<<BB*64, 256, 0, stream>>>(mixed, mean1, istd1, gm, bm,
                                              wh1, wv1, wh2, wv2, att, flag);
        k_stats2  <<<64, 256, 0, stream>>>(att, mean2, istd2);
        k_final2  <<<BB*64, 256, 0, stream>>>(x, mixed, att, gm, bm, gn, bnb,
                                              mean1, istd1, mean2, istd2, d_out, flag);
    } else {
        bf16*  tem   = (bf16*) (ws + 0);
        float* sum1  = (float*)(ws + 4718592);
        float* ss1   = (float*)(ws + 4720896);
        float* mean1 = (float*)(ws + 4723200);
        float* istd1 = (float*)(ws + 4725504);
        float* mean2 = (float*)(ws + 4727808);
        float* istd2 = (float*)(ws + 4728064);
        int*   flag  = (int*)  (ws + 4728320);
        bf16*  att   = tem;

        k_sniff   <<<1, 256, 0, stream>>>((const unsigned int*)x, flag);
        k_pool2   <<<BB*CC*9, 256, 0, stream>>>(x, pool, flag);
        k_zero    <<<1, 256, 0, stream>>>(sum1);
        k_mixstats<<<BB*9*HS, 256, 0, stream>>>(pool, wmix, sum1, ss1, flag);
        k_finstats<<<3, 256, 0, stream>>>(sum1, ss1, mean1, istd1);
        k_tem     <<<BB*HS, 256, 0, stream>>>(pool, wmix, gm, bm, mean1, istd1, tem, flag);
        k_conv_nb <<<BB*64, 256, 0, stream>>>(tem, wh1, wv1, wh2, wv2, att, flag);
        k_stats2  <<<64, 256, 0, stream>>>(att, mean2, istd2);
        k_final_fb<<<BB*HS, 256, 0, stream>>>(x, wmix, att, gm, bm, gn, bnb,
                                              mean1, istd1, mean2, istd2, d_out, flag);
    }
}

// Round 5
// 272.213 us; speedup vs baseline: 5.7130x; 1.6680x over previous
//
#include <hip/hip_runtime.h>
#include <hip/hip_bf16.h>

typedef __hip_bfloat16 bf16;
typedef unsigned short us;
typedef __attribute__((ext_vector_type(8))) short short8;
typedef __attribute__((ext_vector_type(4))) float floatx4;

__device__ __forceinline__ float b2f(bf16 v){ return __bfloat162float(v); }
__device__ __forceinline__ bf16  f2b(float v){ return __float2bfloat16(v); }
__device__ __forceinline__ float ldx(const void* p, size_t i, int isf){
    return isf ? ((const float*)p)[i] : b2f(((const bf16*)p)[i]);
}
__device__ __forceinline__ us bfbits(float v){
    bf16 h = f2b(v); return *(us*)&h;
}
__device__ __forceinline__ float us2f(us u){
    unsigned int w = ((unsigned int)u)<<16; float f; __builtin_memcpy(&f,&w,4); return f;
}

#define BB   16
#define CC   64
#define HH   144
#define WW   144
#define HS   48
#define SP   (HS*HS)            // 2304
#define NTOT (BB*CC*HH*WW)      // 21233664
#define NCH  36864              // B*SP

// -------- 0. dtype sniffer -------------------------------------------------
__global__ void k_sniff(const unsigned int* __restrict__ x, int* __restrict__ flag){
    __shared__ int hit;
    if(threadIdx.x==0) hit = 0;
    __syncthreads();
    int local = 0;
    for(int t=threadIdx.x; t<4096; t+=256){
        unsigned int w = x[t];
        if(((w>>7)&0xFFu)==0xFFu || ((w>>23)&0xFFu)==0xFFu) local = 1;
    }
    if(local) atomicOr(&hit, 1);
    __syncthreads();
    if(threadIdx.x==0) *flag = hit;
}

__global__ void k_zero(float* __restrict__ p){
    for(int i=threadIdx.x; i<1280; i+=256) p[i] = 0.f;
}

// -------- 1. maxpool 3x3 s1 p1, writes FOCUS layout ------------------------
// pf[b][gi][gj][c][y][xx] = maxpool(x)[b,c,3y+gi,3xx+gj]
__global__ __launch_bounds__(256) void k_pool3(const void* __restrict__ x,
                                               us* __restrict__ pf,
                                               const int* __restrict__ flag){
    __shared__ float l [18*148];
    __shared__ float hm[18*148];
    int isf = *flag;
    int bid = blockIdx.x;
    int strip = bid % 9;
    int bc = bid / 9;
    int b = bc>>6, c = bc&63;
    int r0 = strip*16;
    size_t base = (size_t)bc*HH*WW;
    int tid = threadIdx.x;
    // load rows r0-1 .. r0+16 (18 rows x 144), 8-wide vectors
    for(int t=tid; t<18*18; t+=256){
        int row = t/18, ch = t%18;
        int rr = r0-1+row; int c0 = ch*8;
        float v[8];
        if(rr>=0 && rr<HH){
            if(isf){
                const float* xp = (const float*)x + base + (size_t)rr*WW + c0;
                float4 f0 = *(const float4*)xp;
                float4 f1 = *(const float4*)(xp+4);
                v[0]=f0.x;v[1]=f0.y;v[2]=f0.z;v[3]=f0.w;
                v[4]=f1.x;v[5]=f1.y;v[6]=f1.z;v[7]=f1.w;
            } else {
                const us* xp = (const us*)x + base + (size_t)rr*WW + c0;
                uint4 d = *(const uint4*)xp;
                const us* u = (const us*)&d;
                #pragma unroll
                for(int e=0;e<8;++e) v[e] = us2f(u[e]);
            }
        } else {
            #pragma unroll
            for(int e=0;e<8;++e) v[e] = -INFINITY;
        }
        #pragma unroll
        for(int e=0;e<8;++e) l[row*148 + c0 + e] = v[e];
    }
    __syncthreads();
    for(int t=tid; t<18*144; t+=256){
        int row = t/144, cc = t%144;
        float a = l[row*148+cc];
        float bb = (cc>0)   ? l[row*148+cc-1] : -INFINITY;
        float cv = (cc<143) ? l[row*148+cc+1] : -INFINITY;
        hm[row*148+cc] = fmaxf(a, fmaxf(bb,cv));
    }
    __syncthreads();
    // vmax + scatter to focus layout; 4 outputs (same gj) per iter
    for(int t=tid; t<576; t+=256){
        int row = t/36;
        int gj  = (t/12)%3;
        int xg  = t%12;
        int R = r0+row;
        int gi = R%3, y = R/3;
        union { us u[4]; uint2 v; } pk;
        #pragma unroll
        for(int e=0;e<4;++e){
            int xx = xg*4+e; int C = 3*xx+gj;
            float m = fmaxf(hm[row*148+C],
                      fmaxf(hm[(row+1)*148+C], hm[(row+2)*148+C]));
            pk.u[e] = bfbits(m);
        }
        size_t o = ((((size_t)(b*3+gi)*3+gj)*64 + c)*48 + y)*48 + xg*4;
        *(uint2*)&pf[o] = pk.v;
    }
}

// -------- 2. MFMA mixer + BN1 stats ----------------------------------------
// block = (b,g,chunk): C[64 o][288 sites] = W_g[64x64] x I[64x288]
// LDS swizzle: element (row, i) at row*64 + ((i/8 + row)%8)*8 + i%8
__global__ __launch_bounds__(256) void k_mix3(const us* __restrict__ pf,
        const void* __restrict__ wmix, us* __restrict__ mixed,
        float* __restrict__ sum1, float* __restrict__ ss1,
        const int* __restrict__ flag){
    __shared__ __align__(16) us sW[4096];
    __shared__ __align__(16) us sI[288*64];
    __shared__ float sS[64], sQ[64];
    int isf = *flag;
    int bid = blockIdx.x;
    int chunk = bid%8, g = (bid/8)%9, b = bid/72;
    int gi = g/3, gj = g%3;
    int tid = threadIdx.x, lane = tid&63, w = tid>>6;
    // stage W (swizzled): thread -> o=tid/4, i-range 16
    {
        int o  = tid>>2;
        int i0 = (tid&3)*16;
        #pragma unroll
        for(int e=0;e<16;++e){
            int i = i0+e;
            float v = ldx(wmix, (size_t)g*4096 + (size_t)o*64 + i, isf);
            sW[o*64 + ((((i>>3)+o)&7)<<3) + (i&7)] = bfbits(v);
        }
    }
    if(tid<64){ sS[tid]=0.f; sQ[tid]=0.f; }
    // stage I (swizzled): lane = channel i, wave covers 9 vec8 chunks
    {
        int i = lane;
        const us* src = pf + ((((size_t)(b*3+gi)*3+gj)*64 + i)*48 + (size_t)chunk*6)*48;
        for(int vv=w*9; vv<(w+1)*9; ++vv){
            uint4 d = *(const uint4*)(src + vv*8);
            const us* u = (const us*)&d;
            #pragma unroll
            for(int e=0;e<8;++e){
                int s = vv*8+e;
                sI[s*64 + ((((i>>3)+s)&7)<<3) + (i&7)] = u[e];
            }
        }
    }
    __syncthreads();
    int n = lane&15, quad = lane>>4;
    int m = w*16 + n;   // this wave's A rows (o)
    // A fragments for k0=0 (q2=quad) and k0=32 (q2=4+quad)
    short8 a0 = *(const short8*)&sW[m*64 + (((quad     + m)&7)<<3)];
    short8 a1 = *(const short8*)&sW[m*64 + ((((4+quad) + m)&7)<<3)];
    floatx4 acc[18];
    #pragma unroll
    for(int nt=0; nt<18; ++nt) acc[nt] = (floatx4){0.f,0.f,0.f,0.f};
    #pragma unroll
    for(int nt=0; nt<18; ++nt){
        int site = nt*16 + n;
        short8 b0 = *(const short8*)&sI[site*64 + (((quad     + site)&7)<<3)];
        short8 b1 = *(const short8*)&sI[site*64 + ((((4+quad) + site)&7)<<3)];
        acc[nt] = __builtin_amdgcn_mfma_f32_16x16x32_bf16(a0, b0, acc[nt], 0,0,0);
        acc[nt] = __builtin_amdgcn_mfma_f32_16x16x32_bf16(a1, b1, acc[nt], 0,0,0);
    }
    // store + per-lane stats.  C layout: col=lane&15 (site), row=quad*4+r (o)
    size_t obase = (size_t)(b*576 + g*64)*SP + (size_t)chunk*288;
    float s[4] = {0,0,0,0}, q[4] = {0,0,0,0};
    #pragma unroll
    for(int nt=0; nt<18; ++nt){
        #pragma unroll
        for(int r=0;r<4;++r){
            float v = acc[nt][r];
            int o = w*16 + quad*4 + r;
            mixed[obase + (size_t)o*SP + nt*16 + n] = bfbits(v);
            s[r] += v; q[r] += v*v;
        }
    }
    #pragma unroll
    for(int off=1; off<=8; off<<=1){
        #pragma unroll
        for(int r=0;r<4;++r){
            s[r] += __shfl_xor(s[r], off, 64);
            q[r] += __shfl_xor(q[r], off, 64);
        }
    }
    if(n==0){
        #pragma unroll
        for(int r=0;r<4;++r){
            atomicAdd(&sS[w*16+quad*4+r], s[r]);
            atomicAdd(&sQ[w*16+quad*4+r], q[r]);
        }
    }
    __syncthreads();
    if(tid<64){
        atomicAdd(&sum1[g*64+tid], sS[tid]);
        atomicAdd(&ss1 [g*64+tid], sQ[tid]);
    }
}

// -------- 3. finalize BN stats (in place: sum->mean, ss->istd) -------------
__global__ void k_finstats(float* __restrict__ sum, float* __restrict__ ss, int C){
    int t = blockIdx.x*256 + threadIdx.x;
    if(t < C){
        float m = sum[t]/(float)NCH;
        float v = ss[t]/(float)NCH - m*m;
        sum[t] = m;
        ss[t]  = rsqrtf(v + 1e-5f);
    }
}

// -------- 4. fused 4-way depthwise conv + BN1 inline + BN2 stats -----------
__global__ __launch_bounds__(256) void k_conv3(const us* __restrict__ mixed,
    const float* __restrict__ mean1, const float* __restrict__ istd1,
    const void* __restrict__ gm, const void* __restrict__ bm,
    const void* __restrict__ wh1, const void* __restrict__ wv1,
    const void* __restrict__ wh2, const void* __restrict__ wv2,
    us* __restrict__ att, float* __restrict__ sum2, float* __restrict__ ss2,
    const int* __restrict__ flag){
    __shared__ float tile[60*60];
    __shared__ float wt[4*33];
    __shared__ float r1[256], r2[256];
    int isf = *flag;
    int bid = blockIdx.x;
    int b = bid/64, c = bid%64;
    int tid = threadIdx.x;
    for(int t=tid; t<3600; t+=256) tile[t] = 0.f;
    if(tid < 132){
        int which = tid/33, k = tid%33;
        const void* wp = which==0?wh1:which==1?wv1:which==2?wh2:wv2;
        wt[tid] = ldx(wp, c*33 + k, isf);
    }
    __syncthreads();
    float m  = mean1[c];
    float is = istd1[c]*ldx(gm,c,isf);
    float be = ldx(bm,c,isf);
    const us* src = mixed + (size_t)(b*576 + c)*SP;
    for(int t=tid; t<288; t+=256){
        int h = t/6, w0 = (t%6)*8;
        uint4 d = *(const uint4*)(src + t*8);
        const us* u = (const us*)&d;
        #pragma unroll
        for(int e=0;e<8;++e)
            tile[(h+6)*60 + (w0+6) + e] = (us2f(u[e]) - m)*is + be;
    }
    __syncthreads();
    us* out = att + (size_t)(b*64 + c)*SP;
    float sl = 0.f, ql = 0.f;
    for(int t=tid; t<SP; t+=256){
        int h = t/48 + 6, w = t%48 + 6;
        float acc = 0.f;
        #pragma unroll
        for(int u=-5; u<=5; ++u)
            #pragma unroll
            for(int v=-1; v<=1; ++v)
                acc += wt[0*33 + (u+5)*3 + (v+1)] * tile[(h+u)*60 + (w+v)];
        #pragma unroll
        for(int u=-1; u<=1; ++u)
            #pragma unroll
            for(int v=-5; v<=5; ++v)
                acc += wt[1*33 + (u+1)*11 + (v+5)] * tile[(h+u)*60 + (w+v)];
        #pragma unroll
        for(int u=-5; u<=5; ++u)
            #pragma unroll
            for(int v=-1; v<=1; ++v)
                acc += wt[2*33 + (u+5)*3 + (v+1)] * tile[(h+u)*60 + (w+v-u)];
        #pragma unroll
        for(int u=-5; u<=5; ++u)
            #pragma unroll
            for(int v=-1; v<=1; ++v)
                acc += wt[3*33 + (v+1)*11 + (u+5)] * tile[(h+v-u)*60 + (w+u)];
        out[t] = bfbits(acc);
        sl += acc; ql += acc*acc;
    }
    r1[tid]=sl; r2[tid]=ql; __syncthreads();
    for(int o=128;o>0;o>>=1){
        if(tid<o){ r1[tid]+=r1[tid+o]; r2[tid]+=r2[tid+o]; }
        __syncthreads();
    }
    if(tid==0){
        atomicAdd(&sum2[c], r1[0]);
        atomicAdd(&ss2 [c], r2[0]);
    }
}

// -------- 5. final: BN + pixel_shuffle + sigmoid gate (y-split) ------------
__global__ __launch_bounds__(256) void k_final3(const void* __restrict__ x,
    const us* __restrict__ mixed, const us* __restrict__ att,
    const void* __restrict__ gm, const void* __restrict__ bm,
    const void* __restrict__ gn, const void* __restrict__ bnb,
    const float* __restrict__ mean1, const float* __restrict__ istd1,
    const float* __restrict__ mean2, const float* __restrict__ istd2,
    void* __restrict__ out, const int* __restrict__ flag){
    __shared__ __align__(16) us sT[9*1152];
    __shared__ float scs[9], shs[9];
    int isf = *flag;
    int bid = blockIdx.x;
    int half = bid&1, c = (bid>>1)&63, b = bid>>7;
    int yy0 = half*24;
    int tid = threadIdx.x;
    if(tid < 9){
        int f = 9*c + tid;
        float sc, sh;
        if(f < 64){
            sc = istd2[f]*ldx(gn,f,isf);
            sh = ldx(bnb,f,isf) - mean2[f]*sc;
        } else {
            sc = istd1[f]*ldx(gm,f,isf);
            sh = ldx(bm,f,isf) - mean1[f]*sc;
        }
        scs[tid]=sc; shs[tid]=sh;
    }
    for(int t=tid; t<9*144; t+=256){
        int j = t/144, qq = t%144;
        int f = 9*c + j;
        const us* srcp = ((f<64) ? att   + (size_t)(b*64 +f)*SP
                                 : mixed + (size_t)(b*576+f)*SP) + yy0*48;
        ((uint4*)&sT[j*1152])[qq] = ((const uint4*)srcp)[qq];
    }
    __syncthreads();
    size_t pbase = (size_t)(b*64+c)*HH*WW;
    for(int t=tid; t<1296; t+=256){
        int Yl = t/18;
        int Xb = (t%18)*8;
        int yyl = Yl/3, r = Yl%3;
        float vo[8];
        #pragma unroll
        for(int k=0;k<8;++k){
            int X = Xb+k;
            int xx = X/3, sph = X%3;
            int j = 3*r + sph;
            float raw = us2f(sT[j*1152 + yyl*48 + xx]);
            float v = raw*scs[j] + shs[j];
            vo[k] = 1.f/(1.f + __expf(-v));
        }
        size_t off = pbase + (size_t)(yy0*3 + Yl)*WW + Xb;
        if(isf){
            const float4* xp = (const float4*)((const float*)x + off);
            float4 x0 = xp[0], x1 = xp[1];
            float4 o0, o1;
            o0.x = x0.x*vo[0]; o0.y = x0.y*vo[1]; o0.z = x0.z*vo[2]; o0.w = x0.w*vo[3];
            o1.x = x1.x*vo[4]; o1.y = x1.y*vo[5]; o1.z = x1.z*vo[6]; o1.w = x1.w*vo[7];
            float4* op = (float4*)((float*)out + off);
            op[0] = o0; op[1] = o1;
        } else {
            uint4 xr = *(const uint4*)((const us*)x + off);
            const us* xu = (const us*)&xr;
            union { us u[8]; uint4 v; } pk;
            #pragma unroll
            for(int k=0;k<8;++k)
                pk.u[k] = bfbits(us2f(xu[k])*vo[k]);
            *(uint4*)((us*)out + off) = pk.v;
        }
    }
}

// ===========================================================================

extern "C" void kernel_launch(void* const* d_in, const int* in_sizes, int n_in,
                              void* d_out, int out_size, void* d_ws, size_t ws_size,
                              hipStream_t stream) {
    (void)in_sizes; (void)n_in; (void)out_size; (void)ws_size;
    const void* x    = d_in[0];
    const void* wmix = d_in[1];
    const void* gm   = d_in[2];
    const void* bm   = d_in[3];
    const void* wh1  = d_in[4];
    const void* wv1  = d_in[5];
    const void* wh2  = d_in[6];
    const void* wv2  = d_in[7];
    const void* gn   = d_in[8];
    const void* bnb  = d_in[9];

    us* pf = (us*)d_out;          // focus-layout pool in d_out (dead before final)
    char* ws = (char*)d_ws;
    us*    mixed = (us*)   (ws + 0);           // 42467328 B
    us*    att   = (us*)   (ws + 42467328);    //  4718592 B
    float* st1a  = (float*)(ws + 47185920);    // sum1 -> mean1 (576)
    float* st1b  = (float*)(ws + 47188224);    // ss1  -> istd1 (576)
    float* st2a  = (float*)(ws + 47190528);    // sum2 -> mean2 (64)
    float* st2b  = (float*)(ws + 47190784);    // ss2  -> istd2 (64)
    int*   flag  = (int*)  (ws + 47191040);

    k_sniff   <<<1, 256, 0, stream>>>((const unsigned int*)x, flag);
    k_pool3   <<<BB*CC*9, 256, 0, stream>>>(x, pf, flag);
    k_zero    <<<1, 256, 0, stream>>>(st1a);
    k_mix3    <<<BB*9*8, 256, 0, stream>>>(pf, wmix, mixed, st1a, st1b, flag);
    k_finstats<<<3, 256, 0, stream>>>(st1a, st1b, 576);
    k_conv3   <<<BB*64, 256, 0, stream>>>(mixed, st1a, st1b, gm, bm,
                                          wh1, wv1, wh2, wv2, att, st2a, st2b, flag);
    k_finstats<<<1, 64, 0, stream>>>(st2a, st2b, 64);
    k_final3  <<<BB*CC*2, 256, 0, stream>>>(x, mixed, att, gm, bm, gn, bnb,
                                            st1a, st1b, st2a, st2b, d_out, flag);
}